// Round 19
// baseline (301.441 us; speedup 1.0000x reference)
//
#include <hip/hip_runtime.h>

// DST-I spectral Helmholtz solver, NZ=4, NX=NY=2048.
// Even/odd mirror-fold (half FLOPs); B from transposed tables (L3-hot);
// GEMM: 256x256 tile, BK=64 dbuf, 16 waves (4 waves/SIMD for intra-block
// latency hiding), compiler-scheduled interior, ONE __syncthreads per K-tile;
// LDS-staged coalesced C writes; G2 computes H in-epilogue (sin^2 form).

typedef __attribute__((ext_vector_type(8))) short bf16x8;
typedef __attribute__((ext_vector_type(4))) float f32x4;
typedef __attribute__((ext_vector_type(8))) unsigned short ushort8;
typedef __attribute__((ext_vector_type(4))) unsigned short ushort4v;
typedef __attribute__((ext_vector_type(2))) float float2v;

#define LDS_SPACE __attribute__((address_space(3)))
#define GLB_SPACE __attribute__((address_space(1)))

__device__ __forceinline__ void gld_lds16(const unsigned short* g, unsigned short* l) {
  __builtin_amdgcn_global_load_lds((const GLB_SPACE void*)g, (LDS_SPACE void*)l, 16, 0, 0);
}

__device__ __forceinline__ float sinrev(float rev) {   // sin(2*pi*rev), exact arg
  float r;
  asm("v_sin_f32 %0, %1" : "=v"(r) : "v"(rev));
  return r;
}

__device__ __forceinline__ unsigned short f2b(float f) {
  union { float f; unsigned u; } v; v.f = f;
  unsigned r = (v.u + 0x7fffu + ((v.u >> 16) & 1u)) >> 16;  // RNE
  return (unsigned short)r;
}
__device__ __forceinline__ float b2f(unsigned short u) {
  union { unsigned u; float f; } v; v.u = ((unsigned)u) << 16;
  return v.f;
}

// ---- tables: T[tbl][n][k] (transposed), bf16.  0:TE1 1:TO1 2:TE3 3:TO3 ----
__global__ __launch_bounds__(256)
void tables_kernel(unsigned short* __restrict__ T) {
  const int base = (blockIdx.x * 256 + threadIdx.x) * 4;   // < 4*1024*1024
  const int tbl = base >> 20, n = (base >> 10) & 1023, k0 = base & 1023;
  const int cp1 = (tbl & 1) ? 2 * n + 2 : 2 * n + 1;       // j_true+1
  ushort4v v;
#pragma unroll
  for (int e = 0; e < 4; ++e) {
    const int k = k0 + e;
    int a;
    if (tbl < 2) a = k;                                    // natural pair-rep order
    else a = (k < 512) ? 2 * k : (k < 1023 ? 2 * (k - 512) + 1 : 1023);
    const int ph = ((a + 1) * cp1) & 4095;                 // exact phase mod 2*pi
    v[e] = f2b(0.03125f * sinrev((float)ph * (1.0f / 4096.0f)));
  }
  *(ushort4v*)&T[base] = v;
}

// ---- mix + natural fold along y: AE/AO [4*2048 x 1024] bf16 ----
__global__ __launch_bounds__(256)
void mix_fold(const float* __restrict__ q, const float* __restrict__ Cl2m,
              unsigned short* __restrict__ AE, unsigned short* __restrict__ AO) {
  const int idx = blockIdx.x * 256 + threadIdx.x;     // < 2048*1024
  const int x = idx >> 10, u = idx & 1023;
  float c[16];
#pragma unroll
  for (int i = 0; i < 16; ++i) c[i] = Cl2m[i];
  float fe[4] = {0.f, 0.f, 0.f, 0.f}, fo[4] = {0.f, 0.f, 0.f, 0.f};
  if (x < 2047) {
#pragma unroll
    for (int l = 0; l < 4; ++l) {
      const size_t base = ((size_t)l * 2047 + x) * 2047;
      const float qa = q[base + u];
      const float qb = (u < 1023) ? q[base + 2046 - u] : 0.f;
      const float E = (u == 1023) ? qa : qa + qb;
      const float O = (u == 1023) ? 0.f : qa - qb;
#pragma unroll
      for (int m = 0; m < 4; ++m) { fe[m] += c[m * 4 + l] * E; fo[m] += c[m * 4 + l] * O; }
    }
  }
#pragma unroll
  for (int m = 0; m < 4; ++m) {
    AE[((size_t)m * 2048 + x) * 1024 + u] = f2b(fe[m]);
    AO[((size_t)m * 2048 + x) * 1024 + u] = f2b(fo[m]);
  }
}

// ---- transpose + fold (per mode): out[c][u] = in[r1(u)][c] +/- in[r2(u)][c] ----
template <int MAP>
__global__ __launch_bounds__(256)
void tfold(const unsigned short* __restrict__ in, unsigned short* __restrict__ outE,
           unsigned short* __restrict__ outO) {
  __shared__ unsigned short t1[64][72];
  __shared__ unsigned short t2[64][72];
  const size_t ib = (size_t)blockIdx.z * (2048u * 2048u);
  const size_t ob = (size_t)blockIdx.z * (2048u * 1024u);
  const int c0 = blockIdx.x * 64, u0 = blockIdx.y * 64;
  const int t = threadIdx.x;
  const int rr = t >> 3, cc = (t & 7) * 8;
#pragma unroll
  for (int ch = 0; ch < 2; ++ch) {
    const int r = ch * 32 + rr, u = u0 + r;
    const int r1 = (MAP == 0) ? u : (u < 512 ? u : 1024 + (u - 512));
    const int r2 = (MAP == 0) ? 2046 - u : (u < 512 ? 1023 - u : 2046 - (u - 512));
    ushort8 v1 = *(const ushort8*)&in[ib + (size_t)r1 * 2048 + c0 + cc];
    ushort8 v2 = *(const ushort8*)&in[ib + (size_t)r2 * 2048 + c0 + cc];
#pragma unroll
    for (int j = 0; j < 8; ++j) { t1[r][cc + j] = v1[j]; t2[r][cc + j] = v2[j]; }
  }
  __syncthreads();
#pragma unroll
  for (int ch = 0; ch < 2; ++ch) {
    const int r = ch * 32 + rr;
    ushort8 vE, vO;
#pragma unroll
    for (int j = 0; j < 8; ++j) {
      const int uu = u0 + cc + j;
      const float a = b2f(t1[cc + j][r]);
      const float b = b2f(t2[cc + j][r]);
      vE[j] = f2b((uu == 1023) ? a : a + b);
      vO[j] = f2b((uu == 1023) ? 0.f : a - b);
    }
    const size_t o = ob + (size_t)(c0 + r) * 1024 + u0 + cc;
    *(ushort8*)&outE[o] = vE;
    *(ushort8*)&outO[o] = vO;
  }
}

// ---- column fold over interleaved axis (no transpose): pre-G3 ----
__global__ __launch_bounds__(256)
void fold_cols(const unsigned short* __restrict__ R, unsigned short* __restrict__ AE,
               unsigned short* __restrict__ AO) {
  const int idx = blockIdx.x * 256 + threadIdx.x;     // < 8192*1024
  const int row = idx >> 10, u = idx & 1023;
  const int c1 = (u < 512) ? u : (u < 1023 ? 512 + u : 1535);
  const int c2 = (u < 512) ? 1023 - u : (u < 1023 ? 2558 - u : 1535);
  const float a = b2f(R[(size_t)row * 2048 + c1]);
  const float b = b2f(R[(size_t)row * 2048 + c2]);
  AE[(size_t)row * 1024 + u] = f2b((u == 1023) ? a : a + b);
  AO[(size_t)row * 1024 + u] = f2b((u == 1023) ? 0.f : a - b);
}

// ---- GEMM: C_half[8192x1024] = A_half[8192x1024] * T_half^T ----
// 256x256 tile, BK=64 dbuf, 16 waves (4x4 grid, 64x64 per wave), 1 block/CU.
// EPI 0: plain. EPI 1: divide by H computed in-epilogue. EPI 2: + per-mode sum.
#define MFMA_BF16 __builtin_amdgcn_mfma_f32_16x16x32_bf16

template <int EPI>
__global__ __launch_bounds__(1024, 4)
void gemm_eo(const unsigned short* __restrict__ A, const unsigned short* __restrict__ T,
             unsigned short* __restrict__ Cb, const float* __restrict__ H,
             float* __restrict__ sums) {
  __shared__ __align__(16) char lds[131072];  // K-loop: dbuf A|B; epilogue: 256x256 bf16 C
  const int bid = blockIdx.x;
  const int swz = (bid & 7) * 32 + (bid >> 3);      // XCD-bijective (256 % 8 == 0)
  const int h = swz & 1;                            // 0: even(E), 1: odd(O)
  const int bn = (swz >> 1) & 3, bm = swz >> 3;
  const int tid = threadIdx.x;
  const int lane = tid & 63, wave = tid >> 6;
  const int wr = wave >> 2, wc = wave & 3;          // 4 x 4 wave grid (64x64 each)
  const int lr = lane & 15, kg = lane >> 4;
  const int x7 = lr & 7;

  const unsigned short* gA = A + (size_t)h * 8388608u + (size_t)bm * 256 * 1024;
  const unsigned short* gB = T + (size_t)h * 1048576u + (size_t)bn * 256 * 1024;

  // staging: 16B slot ps = tid + i*1024; row = ps>>3; k-col16 = (ps&7)^(row&7)
  const int row0 = tid >> 3;
  const int slot = (tid & 7) ^ (row0 & 7);

  auto stage = [&](int kt, int c) {
    char* lc = lds + c * 65536;
    const size_t ko = (size_t)kt * 64 + slot * 8;
#pragma unroll
    for (int i = 0; i < 2; ++i)
      gld_lds16(gA + (size_t)(row0 + i * 128) * 1024 + ko,
                (unsigned short*)(lc + (tid + i * 1024) * 16));
#pragma unroll
    for (int i = 0; i < 2; ++i)
      gld_lds16(gB + (size_t)(row0 + i * 128) * 1024 + ko,
                (unsigned short*)(lc + 32768 + (tid + i * 1024) * 16));
  };

  f32x4 acc[4][4];
#pragma unroll
  for (int m = 0; m < 4; ++m)
#pragma unroll
    for (int n = 0; n < 4; ++n) acc[m][n] = (f32x4){0.f, 0.f, 0.f, 0.f};

  stage(0, 0);
  stage(1, 1);
  __syncthreads();   // tile 0 (and 1) staging drained + published

  const int arow = wr * 64 + lr;
  const int brow = wc * 64 + lr;
  const LDS_SPACE char* lbase = (const LDS_SPACE char*)lds;

  for (int t = 0; t < 16; ++t) {
    const LDS_SPACE char* la = lbase + (t & 1) * 65536;
    const LDS_SPACE char* lb = la + 32768;

    // per-ks read + MFMA keeps the live fragment set small (acc 64 + 32 frags)
#pragma unroll
    for (int ks = 0; ks < 2; ++ks) {
      bf16x8 av[4], bv[4];
#pragma unroll
      for (int m = 0; m < 4; ++m)
        av[m] = *(const LDS_SPACE bf16x8*)(la + (arow + m * 16) * 128 + (((ks * 4 + kg) ^ x7) << 4));
#pragma unroll
      for (int n = 0; n < 4; ++n)
        bv[n] = *(const LDS_SPACE bf16x8*)(lb + (brow + n * 16) * 128 + (((ks * 4 + kg) ^ x7) << 4));
#pragma unroll
      for (int m = 0; m < 4; ++m)
#pragma unroll
        for (int n = 0; n < 4; ++n)
          acc[m][n] = MFMA_BF16(av[m], bv[n], acc[m][n], 0, 0, 0);
    }

    // ONE barrier per K-tile: all waves done reading buf[t&1]; drains staging
    // issued last iteration (landed: >1 tile in flight) and publishes it.
    __syncthreads();
    if (t < 14) stage(t + 2, t & 1);
  }

  // ---- EPI1 constants: H(a,b) = t(a+1)+t(b+1)-beta, t(x) = -2.5e-7*sin^2(pi*x/4096)
  float beta = 0.f, tA[4];
  bool iok[4] = {true, true, true, true};
  if (EPI == 1) {
    const float s1 = sinrev(1.0f / 8192.0f);
    beta = -5.0e-7f * s1 * s1 - H[(size_t)(bm >> 3) * 4190209u];  // 2*t(1) - H[m][0][0]
#pragma unroll
    for (int n = 0; n < 4; ++n) {
      const int ia = 2 * (bn * 256 + wc * 64 + n * 16 + lr) + h;  // i_true
      iok[n] = ia < 2047;
      const float s = sinrev((float)(ia + 1) * (1.0f / 8192.0f));
      tA[n] = -2.5e-7f * s * s;
    }
  }

  // ---- stage C tile into LDS (XOR-swizzled 16B slots within each 512B row)
  float ssum = 0.f;
#pragma unroll
  for (int m = 0; m < 4; ++m) {
#pragma unroll
    for (int j = 0; j < 4; ++j) {
      const int row_l = wr * 64 + m * 16 + kg * 4 + j;
      float tB = 0.f;
      bool jok = true;
      if (EPI == 1) {
        const int jint = (bm * 256 + row_l) & 2047;
        const int j_true = 2 * (jint & 1023) + (jint >> 10);
        jok = j_true < 2047;
        const float s = sinrev((float)(j_true + 1) * (1.0f / 8192.0f));
        tB = -2.5e-7f * s * s;
      }
#pragma unroll
      for (int n = 0; n < 4; ++n) {
        const int col_l = wc * 64 + n * 16 + lr;
        float v = acc[m][n][j];
        if (EPI == 1) {
          const float Hv = tA[n] + tB - beta;
          float r = __builtin_amdgcn_rcpf(Hv);
          r = r * (2.0f - Hv * r);           // 1 NR step
          v = (iok[n] && jok) ? v * r : 0.f;
        }
        if (EPI == 2) ssum += v;
        const int byte = row_l * 512 + ((((col_l >> 3) ^ (row_l & 7)) << 4)) + (col_l & 7) * 2;
        *(unsigned short*)&lds[byte] = f2b(v);
      }
    }
  }
  __syncthreads();

  // ---- coalesced flush: 256 rows x 512B contiguous (8 passes x 1024 thr x 16B)
  unsigned short* gC = Cb + (size_t)(bm * 256) * 2048 + h * 1024 + bn * 256;
#pragma unroll
  for (int p = 0; p < 8; ++p) {
    const int c = p * 1024 + tid;
    const int r = c >> 5, c16 = c & 31;
    const bf16x8 vv = *(const bf16x8*)&lds[r * 512 + ((c16 ^ (r & 7)) << 4)];
    *(bf16x8*)&gC[(size_t)r * 2048 + c16 * 8] = vv;
  }

  if (EPI == 2) {
#pragma unroll
    for (int off = 32; off > 0; off >>= 1) ssum += __shfl_xor(ssum, off);
    if (lane == 0) atomicAdd(&sums[bm >> 3], ssum);
  }
}

// ---- final: de-interleave, homogeneous correction, mode->layer mix ----
// One thread per (x, y-pair): both V gathers become coalesced streams.
__global__ __launch_bounds__(256)
void final_kernel(const unsigned short* __restrict__ V, const float* __restrict__ homsol,
                  const float* __restrict__ hm, const float* __restrict__ Cm2l,
                  const float* __restrict__ sums, float* __restrict__ out) {
  const int pp = blockIdx.x * 256 + threadIdx.x;    // < 2049*1025
  if (pp >= 2049 * 1025) return;
  const int x = pp / 1025, yy = pp - x * 1025;
  const int y0 = 2 * yy;                            // even y
  const bool has1 = (y0 + 1) <= 2048;               // odd y exists
  const bool xin = (x >= 1) && (x <= 2047);
  const bool in0 = xin && (yy >= 1) && (y0 <= 2047);
  const bool in1 = xin && has1 && (y0 + 1 <= 2047);
  const int row = (x >= 1) ? (((x - 1) & 1) ? 1024 + ((x - 1) >> 1) : ((x - 1) >> 1)) : 0;
  const int col0 = 1024 + yy - 1;                   // yt0 = 2yy-1 odd
  const int col1 = yy;                              // yt1 = 2yy even
  const size_t p0 = (size_t)x * 2049 + y0;

  float pm0[4], pm1[4];
#pragma unroll
  for (int m = 0; m < 4; ++m) {
    const size_t vb = (size_t)m * 4194304u + (size_t)row * 2048;
    const float i0 = in0 ? b2f(V[vb + col0]) : 0.f;
    const float i1 = in1 ? b2f(V[vb + col1]) : 0.f;
    const float alpha = -(sums[m] * (1.0f / 4194304.0f)) / hm[m];
    const size_t hb = (size_t)m * 4198401u + p0;
    pm0[m] = i0 + alpha * homsol[hb];
    pm1[m] = has1 ? (i1 + alpha * homsol[hb + 1]) : 0.f;
  }
#pragma unroll
  for (int l = 0; l < 4; ++l) {
    const float o0 = Cm2l[l * 4 + 0] * pm0[0] + Cm2l[l * 4 + 1] * pm0[1] +
                     Cm2l[l * 4 + 2] * pm0[2] + Cm2l[l * 4 + 3] * pm0[3];
    const size_t ob = (size_t)l * 4198401u + p0;
    if (has1) {
      const float o1 = Cm2l[l * 4 + 0] * pm1[0] + Cm2l[l * 4 + 1] * pm1[1] +
                       Cm2l[l * 4 + 2] * pm1[2] + Cm2l[l * 4 + 3] * pm1[3];
      float2v o; o[0] = o0; o[1] = o1;
      *(float2v*)&out[ob] = o;
    } else {
      out[ob] = o0;
    }
  }
}

extern "C" void kernel_launch(void* const* d_in, const int* in_sizes, int n_in,
                              void* d_out, int out_size, void* d_ws, size_t ws_size,
                              hipStream_t stream) {
  const float* q     = (const float*)d_in[0];   // [4,2047,2047]
  const float* Cl2m  = (const float*)d_in[1];   // [4,4]
  const float* Cm2l  = (const float*)d_in[2];   // [4,4]
  const float* H     = (const float*)d_in[3];   // [4,2047,2047]
  const float* hom   = (const float*)d_in[4];   // [4,2049,2049]
  const float* hmean = (const float*)d_in[5];   // [4]
  float* out = (float*)d_out;

  char* ws = (char*)d_ws;
  unsigned short* Tb = (unsigned short*)ws;                    //  8 MB: TE1|TO1|TE3|TO3
  unsigned short* Aslot = (unsigned short*)(ws + 8388608u);    // 32 MB: [E half | O half]
  unsigned short* Bslot = (unsigned short*)(ws + 41943040u);   // 32 MB
  float* sums        = (float*)(ws + 75497472u);               // 16 B
  unsigned short* AO = Aslot + 8388608u;                       // O-half base

  tables_kernel<<<4096, 256, 0, stream>>>(Tb);
  mix_fold<<<8192, 256, 0, stream>>>(q, Cl2m, Aslot, AO);
  hipMemsetAsync(sums, 0, 16, stream);

  const dim3 tg(32, 16, 4);
  // G1: Q1 = fold(P) x S  (DST along y)
  gemm_eo<0><<<256, 1024, 0, stream>>>(Aslot, Tb, Bslot, nullptr, nullptr);
  // transpose + natural fold over x
  tfold<0><<<tg, 256, 0, stream>>>(Bslot, Aslot, AO);
  // G2: R = (fold(Q1^T) x S) / H  (DST along x; H computed in-epilogue)
  gemm_eo<1><<<256, 1024, 0, stream>>>(Aslot, Tb, Bslot, H, nullptr);
  // interleaved column fold over spectral-x
  fold_cols<<<32768, 256, 0, stream>>>(Bslot, Aslot, AO);
  // G3: U = fold(R) x S  (inverse DST step 1) -- interleaved-fold tables
  gemm_eo<0><<<256, 1024, 0, stream>>>(Aslot, Tb + 2097152u, Bslot, nullptr, nullptr);
  // transpose + interleaved fold over spectral-y
  tfold<1><<<tg, 256, 0, stream>>>(Bslot, Aslot, AO);
  // G4: V = fold(U^T) x S (+ per-mode sum)
  gemm_eo<2><<<256, 1024, 0, stream>>>(Aslot, Tb + 2097152u, Bslot, nullptr, sums);

  final_kernel<<<8205, 256, 0, stream>>>(Bslot, hom, hmean, Cm2l, sums, out);
}

// Round 20
// 266.256 us; speedup vs baseline: 1.1321x; 1.1321x over previous
//
#include <hip/hip_runtime.h>

// DST-I spectral Helmholtz solver, NZ=4, NX=NY=2048.  [r18 — best measured]
// Even/odd mirror-fold (half FLOPs); B from transposed tables (L3-hot);
// GEMM: 256x256 tile, BK=64 dbuf, 8 waves, compiler-scheduled interior,
// ONE __syncthreads per K-tile; LDS-staged coalesced C writes; G2 computes
// H in-epilogue (sin^2 form); pair-coalesced final kernel.

typedef __attribute__((ext_vector_type(8))) short bf16x8;
typedef __attribute__((ext_vector_type(4))) float f32x4;
typedef __attribute__((ext_vector_type(8))) unsigned short ushort8;
typedef __attribute__((ext_vector_type(4))) unsigned short ushort4v;
typedef __attribute__((ext_vector_type(2))) float float2v;

#define LDS_SPACE __attribute__((address_space(3)))
#define GLB_SPACE __attribute__((address_space(1)))

__device__ __forceinline__ void gld_lds16(const unsigned short* g, unsigned short* l) {
  __builtin_amdgcn_global_load_lds((const GLB_SPACE void*)g, (LDS_SPACE void*)l, 16, 0, 0);
}

__device__ __forceinline__ float sinrev(float rev) {   // sin(2*pi*rev), exact arg
  float r;
  asm("v_sin_f32 %0, %1" : "=v"(r) : "v"(rev));
  return r;
}

__device__ __forceinline__ unsigned short f2b(float f) {
  union { float f; unsigned u; } v; v.f = f;
  unsigned r = (v.u + 0x7fffu + ((v.u >> 16) & 1u)) >> 16;  // RNE
  return (unsigned short)r;
}
__device__ __forceinline__ float b2f(unsigned short u) {
  union { unsigned u; float f; } v; v.u = ((unsigned)u) << 16;
  return v.f;
}

// ---- tables: T[tbl][n][k] (transposed), bf16.  0:TE1 1:TO1 2:TE3 3:TO3 ----
__global__ __launch_bounds__(256)
void tables_kernel(unsigned short* __restrict__ T) {
  const int base = (blockIdx.x * 256 + threadIdx.x) * 4;   // < 4*1024*1024
  const int tbl = base >> 20, n = (base >> 10) & 1023, k0 = base & 1023;
  const int cp1 = (tbl & 1) ? 2 * n + 2 : 2 * n + 1;       // j_true+1
  ushort4v v;
#pragma unroll
  for (int e = 0; e < 4; ++e) {
    const int k = k0 + e;
    int a;
    if (tbl < 2) a = k;                                    // natural pair-rep order
    else a = (k < 512) ? 2 * k : (k < 1023 ? 2 * (k - 512) + 1 : 1023);
    const int ph = ((a + 1) * cp1) & 4095;                 // exact phase mod 2*pi
    v[e] = f2b(0.03125f * sinrev((float)ph * (1.0f / 4096.0f)));
  }
  *(ushort4v*)&T[base] = v;
}

// ---- mix + natural fold along y: AE/AO [4*2048 x 1024] bf16 ----
__global__ __launch_bounds__(256)
void mix_fold(const float* __restrict__ q, const float* __restrict__ Cl2m,
              unsigned short* __restrict__ AE, unsigned short* __restrict__ AO) {
  const int idx = blockIdx.x * 256 + threadIdx.x;     // < 2048*1024
  const int x = idx >> 10, u = idx & 1023;
  float c[16];
#pragma unroll
  for (int i = 0; i < 16; ++i) c[i] = Cl2m[i];
  float fe[4] = {0.f, 0.f, 0.f, 0.f}, fo[4] = {0.f, 0.f, 0.f, 0.f};
  if (x < 2047) {
#pragma unroll
    for (int l = 0; l < 4; ++l) {
      const size_t base = ((size_t)l * 2047 + x) * 2047;
      const float qa = q[base + u];
      const float qb = (u < 1023) ? q[base + 2046 - u] : 0.f;
      const float E = (u == 1023) ? qa : qa + qb;
      const float O = (u == 1023) ? 0.f : qa - qb;
#pragma unroll
      for (int m = 0; m < 4; ++m) { fe[m] += c[m * 4 + l] * E; fo[m] += c[m * 4 + l] * O; }
    }
  }
#pragma unroll
  for (int m = 0; m < 4; ++m) {
    AE[((size_t)m * 2048 + x) * 1024 + u] = f2b(fe[m]);
    AO[((size_t)m * 2048 + x) * 1024 + u] = f2b(fo[m]);
  }
}

// ---- transpose + fold (per mode): out[c][u] = in[r1(u)][c] +/- in[r2(u)][c] ----
template <int MAP>
__global__ __launch_bounds__(256)
void tfold(const unsigned short* __restrict__ in, unsigned short* __restrict__ outE,
           unsigned short* __restrict__ outO) {
  __shared__ unsigned short t1[64][72];
  __shared__ unsigned short t2[64][72];
  const size_t ib = (size_t)blockIdx.z * (2048u * 2048u);
  const size_t ob = (size_t)blockIdx.z * (2048u * 1024u);
  const int c0 = blockIdx.x * 64, u0 = blockIdx.y * 64;
  const int t = threadIdx.x;
  const int rr = t >> 3, cc = (t & 7) * 8;
#pragma unroll
  for (int ch = 0; ch < 2; ++ch) {
    const int r = ch * 32 + rr, u = u0 + r;
    const int r1 = (MAP == 0) ? u : (u < 512 ? u : 1024 + (u - 512));
    const int r2 = (MAP == 0) ? 2046 - u : (u < 512 ? 1023 - u : 2046 - (u - 512));
    ushort8 v1 = *(const ushort8*)&in[ib + (size_t)r1 * 2048 + c0 + cc];
    ushort8 v2 = *(const ushort8*)&in[ib + (size_t)r2 * 2048 + c0 + cc];
#pragma unroll
    for (int j = 0; j < 8; ++j) { t1[r][cc + j] = v1[j]; t2[r][cc + j] = v2[j]; }
  }
  __syncthreads();
#pragma unroll
  for (int ch = 0; ch < 2; ++ch) {
    const int r = ch * 32 + rr;
    ushort8 vE, vO;
#pragma unroll
    for (int j = 0; j < 8; ++j) {
      const int uu = u0 + cc + j;
      const float a = b2f(t1[cc + j][r]);
      const float b = b2f(t2[cc + j][r]);
      vE[j] = f2b((uu == 1023) ? a : a + b);
      vO[j] = f2b((uu == 1023) ? 0.f : a - b);
    }
    const size_t o = ob + (size_t)(c0 + r) * 1024 + u0 + cc;
    *(ushort8*)&outE[o] = vE;
    *(ushort8*)&outO[o] = vO;
  }
}

// ---- column fold over interleaved axis (no transpose): pre-G3 ----
__global__ __launch_bounds__(256)
void fold_cols(const unsigned short* __restrict__ R, unsigned short* __restrict__ AE,
               unsigned short* __restrict__ AO) {
  const int idx = blockIdx.x * 256 + threadIdx.x;     // < 8192*1024
  const int row = idx >> 10, u = idx & 1023;
  const int c1 = (u < 512) ? u : (u < 1023 ? 512 + u : 1535);
  const int c2 = (u < 512) ? 1023 - u : (u < 1023 ? 2558 - u : 1535);
  const float a = b2f(R[(size_t)row * 2048 + c1]);
  const float b = b2f(R[(size_t)row * 2048 + c2]);
  AE[(size_t)row * 1024 + u] = f2b((u == 1023) ? a : a + b);
  AO[(size_t)row * 1024 + u] = f2b((u == 1023) ? 0.f : a - b);
}

// ---- GEMM: C_half[8192x1024] = A_half[8192x1024] * T_half^T ----
// EPI 0: plain. EPI 1: divide by H computed in-epilogue. EPI 2: + per-mode sum.
#define MFMA_BF16 __builtin_amdgcn_mfma_f32_16x16x32_bf16

template <int EPI>
__global__ __launch_bounds__(512, 2)
void gemm_eo(const unsigned short* __restrict__ A, const unsigned short* __restrict__ T,
             unsigned short* __restrict__ Cb, const float* __restrict__ H,
             float* __restrict__ sums) {
  __shared__ __align__(16) char lds[131072];  // K-loop: dbuf A|B; epilogue: 256x256 bf16 C
  const int bid = blockIdx.x;
  const int swz = (bid & 7) * 32 + (bid >> 3);      // XCD-bijective (256 % 8 == 0)
  const int h = swz & 1;                            // 0: even(E), 1: odd(O)
  const int bn = (swz >> 1) & 3, bm = swz >> 3;
  const int tid = threadIdx.x;
  const int lane = tid & 63, wave = tid >> 6;
  const int wr = wave >> 2, wc = wave & 3;          // 2 x 4 wave grid
  const int lr = lane & 15, kg = lane >> 4;
  const int x7 = lr & 7;

  const unsigned short* gA = A + (size_t)h * 8388608u + (size_t)bm * 256 * 1024;
  const unsigned short* gB = T + (size_t)h * 1048576u + (size_t)bn * 256 * 1024;

  // staging: 16B slot ps = tid + i*512; row = ps>>3; k-col16 = (ps&7)^(row&7)
  const int row0 = tid >> 3;
  const int slot = (tid & 7) ^ (row0 & 7);

  auto stage = [&](int kt, int c) {
    char* lc = lds + c * 65536;
    const size_t ko = (size_t)kt * 64 + slot * 8;
#pragma unroll
    for (int i = 0; i < 4; ++i)
      gld_lds16(gA + (size_t)(row0 + i * 64) * 1024 + ko,
                (unsigned short*)(lc + (tid + i * 512) * 16));
#pragma unroll
    for (int i = 0; i < 4; ++i)
      gld_lds16(gB + (size_t)(row0 + i * 64) * 1024 + ko,
                (unsigned short*)(lc + 32768 + (tid + i * 512) * 16));
  };

  f32x4 acc[8][4];
#pragma unroll
  for (int m = 0; m < 8; ++m)
#pragma unroll
    for (int n = 0; n < 4; ++n) acc[m][n] = (f32x4){0.f, 0.f, 0.f, 0.f};

  stage(0, 0);
  stage(1, 1);
  __syncthreads();   // tile 0 (and 1) staging drained + published

  const int arow = wr * 128 + lr;
  const int brow = wc * 64 + lr;
  const LDS_SPACE char* lbase = (const LDS_SPACE char*)lds;

  for (int t = 0; t < 16; ++t) {
    const LDS_SPACE char* la = lbase + (t & 1) * 65536;
    const LDS_SPACE char* lb = la + 32768;

    bf16x8 al[4][2], ah[4][2], bl[2][2], bh[2][2];

    // plain LDS vector loads — compiler schedules reads<->MFMAs with counted lgkmcnt
#pragma unroll
    for (int m = 0; m < 4; ++m)
#pragma unroll
      for (int ks = 0; ks < 2; ++ks)
        al[m][ks] = *(const LDS_SPACE bf16x8*)(la + (arow + m * 16) * 128 + (((ks * 4 + kg) ^ x7) << 4));
#pragma unroll
    for (int n = 0; n < 2; ++n)
#pragma unroll
      for (int ks = 0; ks < 2; ++ks)
        bl[n][ks] = *(const LDS_SPACE bf16x8*)(lb + (brow + n * 16) * 128 + (((ks * 4 + kg) ^ x7) << 4));
#pragma unroll
    for (int ks = 0; ks < 2; ++ks)
#pragma unroll
      for (int m = 0; m < 4; ++m)
#pragma unroll
        for (int n = 0; n < 2; ++n)
          acc[m][n] = MFMA_BF16(al[m][ks], bl[n][ks], acc[m][n], 0, 0, 0);

#pragma unroll
    for (int n = 0; n < 2; ++n)
#pragma unroll
      for (int ks = 0; ks < 2; ++ks)
        bh[n][ks] = *(const LDS_SPACE bf16x8*)(lb + (brow + (n + 2) * 16) * 128 + (((ks * 4 + kg) ^ x7) << 4));
#pragma unroll
    for (int ks = 0; ks < 2; ++ks)
#pragma unroll
      for (int m = 0; m < 4; ++m)
#pragma unroll
        for (int n = 0; n < 2; ++n)
          acc[m][n + 2] = MFMA_BF16(al[m][ks], bh[n][ks], acc[m][n + 2], 0, 0, 0);

#pragma unroll
    for (int m = 0; m < 4; ++m)
#pragma unroll
      for (int ks = 0; ks < 2; ++ks)
        ah[m][ks] = *(const LDS_SPACE bf16x8*)(la + (arow + (m + 4) * 16) * 128 + (((ks * 4 + kg) ^ x7) << 4));
#pragma unroll
    for (int ks = 0; ks < 2; ++ks)
#pragma unroll
      for (int m = 0; m < 4; ++m)
#pragma unroll
        for (int n = 0; n < 2; ++n)
          acc[m + 4][n + 2] = MFMA_BF16(ah[m][ks], bh[n][ks], acc[m + 4][n + 2], 0, 0, 0);
#pragma unroll
    for (int ks = 0; ks < 2; ++ks)
#pragma unroll
      for (int m = 0; m < 4; ++m)
#pragma unroll
        for (int n = 0; n < 2; ++n)
          acc[m + 4][n] = MFMA_BF16(ah[m][ks], bl[n][ks], acc[m + 4][n], 0, 0, 0);

    // ONE barrier per K-tile: all waves done reading buf[t&1]; drains staging
    // issued last iteration (landed: >1 tile in flight) and publishes it.
    __syncthreads();
    if (t < 14) stage(t + 2, t & 1);
  }

  // ---- EPI1 constants: H(a,b) = t(a+1)+t(b+1)-beta, t(x) = -2.5e-7*sin^2(pi*x/4096)
  float beta = 0.f, tA[4];
  bool iok[4] = {true, true, true, true};
  if (EPI == 1) {
    const float s1 = sinrev(1.0f / 8192.0f);
    beta = -5.0e-7f * s1 * s1 - H[(size_t)(bm >> 3) * 4190209u];  // 2*t(1) - H[m][0][0]
#pragma unroll
    for (int n = 0; n < 4; ++n) {
      const int ia = 2 * (bn * 256 + wc * 64 + n * 16 + lr) + h;  // i_true
      iok[n] = ia < 2047;
      const float s = sinrev((float)(ia + 1) * (1.0f / 8192.0f));
      tA[n] = -2.5e-7f * s * s;
    }
  }

  // ---- stage C tile into LDS (XOR-swizzled 16B slots within each 512B row)
  float ssum = 0.f;
#pragma unroll
  for (int m = 0; m < 8; ++m) {
#pragma unroll
    for (int j = 0; j < 4; ++j) {
      const int row_l = wr * 128 + m * 16 + kg * 4 + j;
      float tB = 0.f;
      bool jok = true;
      if (EPI == 1) {
        const int jint = (bm * 256 + row_l) & 2047;
        const int j_true = 2 * (jint & 1023) + (jint >> 10);
        jok = j_true < 2047;
        const float s = sinrev((float)(j_true + 1) * (1.0f / 8192.0f));
        tB = -2.5e-7f * s * s;
      }
#pragma unroll
      for (int n = 0; n < 4; ++n) {
        const int col_l = wc * 64 + n * 16 + lr;
        float v = acc[m][n][j];
        if (EPI == 1) {
          const float Hv = tA[n] + tB - beta;
          float r = __builtin_amdgcn_rcpf(Hv);
          r = r * (2.0f - Hv * r);           // 1 NR step
          v = (iok[n] && jok) ? v * r : 0.f;
        }
        if (EPI == 2) ssum += v;
        const int byte = row_l * 512 + ((((col_l >> 3) ^ (row_l & 7)) << 4)) + (col_l & 7) * 2;
        *(unsigned short*)&lds[byte] = f2b(v);
      }
    }
  }
  __syncthreads();

  // ---- coalesced flush: 256 rows x 512B contiguous
  unsigned short* gC = Cb + (size_t)(bm * 256) * 2048 + h * 1024 + bn * 256;
#pragma unroll
  for (int p = 0; p < 16; ++p) {
    const int c = p * 512 + tid;
    const int r = c >> 5, c16 = c & 31;
    const bf16x8 vv = *(const bf16x8*)&lds[r * 512 + ((c16 ^ (r & 7)) << 4)];
    *(bf16x8*)&gC[(size_t)r * 2048 + c16 * 8] = vv;
  }

  if (EPI == 2) {
#pragma unroll
    for (int off = 32; off > 0; off >>= 1) ssum += __shfl_xor(ssum, off);
    if (lane == 0) atomicAdd(&sums[bm >> 3], ssum);
  }
}

// ---- final: de-interleave, homogeneous correction, mode->layer mix ----
// One thread per (x, y-pair): both V gathers become coalesced streams.
__global__ __launch_bounds__(256)
void final_kernel(const unsigned short* __restrict__ V, const float* __restrict__ homsol,
                  const float* __restrict__ hm, const float* __restrict__ Cm2l,
                  const float* __restrict__ sums, float* __restrict__ out) {
  const int pp = blockIdx.x * 256 + threadIdx.x;    // < 2049*1025
  if (pp >= 2049 * 1025) return;
  const int x = pp / 1025, yy = pp - x * 1025;
  const int y0 = 2 * yy;                            // even y
  const bool has1 = (y0 + 1) <= 2048;               // odd y exists
  const bool xin = (x >= 1) && (x <= 2047);
  const bool in0 = xin && (yy >= 1) && (y0 <= 2047);
  const bool in1 = xin && has1 && (y0 + 1 <= 2047);
  const int row = (x >= 1) ? (((x - 1) & 1) ? 1024 + ((x - 1) >> 1) : ((x - 1) >> 1)) : 0;
  const int col0 = 1024 + yy - 1;                   // yt0 = 2yy-1 odd
  const int col1 = yy;                              // yt1 = 2yy even
  const size_t p0 = (size_t)x * 2049 + y0;

  float pm0[4], pm1[4];
#pragma unroll
  for (int m = 0; m < 4; ++m) {
    const size_t vb = (size_t)m * 4194304u + (size_t)row * 2048;
    const float i0 = in0 ? b2f(V[vb + col0]) : 0.f;
    const float i1 = in1 ? b2f(V[vb + col1]) : 0.f;
    const float alpha = -(sums[m] * (1.0f / 4194304.0f)) / hm[m];
    const size_t hb = (size_t)m * 4198401u + p0;
    pm0[m] = i0 + alpha * homsol[hb];
    pm1[m] = has1 ? (i1 + alpha * homsol[hb + 1]) : 0.f;
  }
#pragma unroll
  for (int l = 0; l < 4; ++l) {
    const float o0 = Cm2l[l * 4 + 0] * pm0[0] + Cm2l[l * 4 + 1] * pm0[1] +
                     Cm2l[l * 4 + 2] * pm0[2] + Cm2l[l * 4 + 3] * pm0[3];
    const size_t ob = (size_t)l * 4198401u + p0;
    if (has1) {
      const float o1 = Cm2l[l * 4 + 0] * pm1[0] + Cm2l[l * 4 + 1] * pm1[1] +
                       Cm2l[l * 4 + 2] * pm1[2] + Cm2l[l * 4 + 3] * pm1[3];
      float2v o; o[0] = o0; o[1] = o1;
      *(float2v*)&out[ob] = o;
    } else {
      out[ob] = o0;
    }
  }
}

extern "C" void kernel_launch(void* const* d_in, const int* in_sizes, int n_in,
                              void* d_out, int out_size, void* d_ws, size_t ws_size,
                              hipStream_t stream) {
  const float* q     = (const float*)d_in[0];   // [4,2047,2047]
  const float* Cl2m  = (const float*)d_in[1];   // [4,4]
  const float* Cm2l  = (const float*)d_in[2];   // [4,4]
  const float* H     = (const float*)d_in[3];   // [4,2047,2047]
  const float* hom   = (const float*)d_in[4];   // [4,2049,2049]
  const float* hmean = (const float*)d_in[5];   // [4]
  float* out = (float*)d_out;

  char* ws = (char*)d_ws;
  unsigned short* Tb = (unsigned short*)ws;                    //  8 MB: TE1|TO1|TE3|TO3
  unsigned short* Aslot = (unsigned short*)(ws + 8388608u);    // 32 MB: [E half | O half]
  unsigned short* Bslot = (unsigned short*)(ws + 41943040u);   // 32 MB
  float* sums        = (float*)(ws + 75497472u);               // 16 B
  unsigned short* AO = Aslot + 8388608u;                       // O-half base

  tables_kernel<<<4096, 256, 0, stream>>>(Tb);
  mix_fold<<<8192, 256, 0, stream>>>(q, Cl2m, Aslot, AO);
  hipMemsetAsync(sums, 0, 16, stream);

  const dim3 tg(32, 16, 4);
  // G1: Q1 = fold(P) x S  (DST along y)
  gemm_eo<0><<<256, 512, 0, stream>>>(Aslot, Tb, Bslot, nullptr, nullptr);
  // transpose + natural fold over x
  tfold<0><<<tg, 256, 0, stream>>>(Bslot, Aslot, AO);
  // G2: R = (fold(Q1^T) x S) / H  (DST along x; H computed in-epilogue)
  gemm_eo<1><<<256, 512, 0, stream>>>(Aslot, Tb, Bslot, H, nullptr);
  // interleaved column fold over spectral-x
  fold_cols<<<32768, 256, 0, stream>>>(Bslot, Aslot, AO);
  // G3: U = fold(R) x S  (inverse DST step 1) -- interleaved-fold tables
  gemm_eo<0><<<256, 512, 0, stream>>>(Aslot, Tb + 2097152u, Bslot, nullptr, nullptr);
  // transpose + interleaved fold over spectral-y
  tfold<1><<<tg, 256, 0, stream>>>(Bslot, Aslot, AO);
  // G4: V = fold(U^T) x S (+ per-mode sum)
  gemm_eo<2><<<256, 512, 0, stream>>>(Aslot, Tb + 2097152u, Bslot, nullptr, sums);

  final_kernel<<<8205, 256, 0, stream>>>(Bslot, hom, hmean, Cm2l, sums, out);
}